// Round 13
// baseline (431.756 us; speedup 1.0000x reference)
//
#include <hip/hip_runtime.h>

#define B_ 32
#define C_ 512
#define HW_ 4096
#define N_ 80
#define REPS 4  // measurement: idempotent reps; remove after diagnosis

typedef __bf16 bf16x8 __attribute__((ext_vector_type(8)));
typedef __bf16 bf16x4 __attribute__((ext_vector_type(4)));
typedef float f32x4 __attribute__((ext_vector_type(4)));
typedef unsigned short u16x8 __attribute__((ext_vector_type(8)));

__device__ __forceinline__ void gload_lds16(const void* g, void* l) {
  __builtin_amdgcn_global_load_lds((const __attribute__((address_space(1))) void*)g,
                                   (__attribute__((address_space(3))) void*)l, 16, 0, 0);
}

#define VMCNT(n) asm volatile("s_waitcnt vmcnt(" #n ")" ::: "memory")
#define SBAR() asm volatile("s_barrier" ::: "memory")

// ---------------------------------------------------------------------------
// K0: refragment W -> Wfrag bf16 (MFMA B-operand unit layout) AND zero denom.
// ---------------------------------------------------------------------------
__global__ __launch_bounds__(256) void k0_wfrag(const float* __restrict__ W,
                                                __bf16* __restrict__ Wfrag,
                                                float* __restrict__ denom) {
  const int t = blockIdx.x * 256 + threadIdx.x;
  if (t < B_ * N_) denom[t] = 0.f;
  if (t >= 16 * 5 * 64) return;
  const int cs = t / 320, rem = t % 320;
  const int nf = rem >> 6, lane = rem & 63;
  const int n = nf * 16 + (lane & 15);
  const int c = cs * 32 + (lane >> 4) * 8;
  const float* wp = W + (size_t)n * C_ + c;
  bf16x8 v;
#pragma unroll
  for (int i = 0; i < 8; ++i) v[i] = (__bf16)wp[i];
  *(bf16x8*)(Wfrag + (size_t)t * 8) = v;
}

// ---------------------------------------------------------------------------
// K1 (REPS-instrumented): E = exp(feats^T W^T); denom += row sums (last rep).
// Structure identical to R11. Grid (HW/128, B), 4 waves, 3 blocks/CU.
// ---------------------------------------------------------------------------
#define K1_STAGE(CS, SLOT)                                                      \
  {                                                                             \
    _Pragma("unroll") for (int j = 0; j < 4; ++j) {                             \
      const int d = j * 256 + tid;                                              \
      const int r = d >> 5, p = d & 31;                                         \
      gload_lds16(fb + (size_t)((CS)*32 + r) * HW_ + htile0 + p * 4,            \
                  (char*)tile + (SLOT)*16384 + (j * 256 + wave * 64) * 16);     \
    }                                                                           \
  }

#define K1_WLOAD(W, CS)                                                         \
  {                                                                             \
    _Pragma("unroll") for (int nf = 0; nf < 5; ++nf)                            \
        W[nf] = *(const u16x8*)(Wfrag + ((size_t)((CS)*5 + nf) * 64 + lane) * 8); \
  }

#define K1_COMPUTE(T, WU)                                                       \
  {                                                                             \
    const float* tb = (const float*)((char*)tile + ((T) % 3) * 16384);          \
    bf16x8 afr[2];                                                              \
    _Pragma("unroll") for (int hf = 0; hf < 2; ++hf) {                          \
      const int col = wave * 32 + hf * 16 + l16;                                \
      _Pragma("unroll") for (int i = 0; i < 8; ++i)                             \
          afr[hf][i] = (__bf16)tb[(quad * 8 + i) * 128 + col];                  \
    }                                                                           \
    _Pragma("unroll") for (int nf = 0; nf < 5; ++nf) {                          \
      const bf16x8 bfr = __builtin_bit_cast(bf16x8, WU[nf]);                    \
      acc[0][nf] = __builtin_amdgcn_mfma_f32_16x16x32_bf16(afr[0], bfr, acc[0][nf], 0, 0, 0); \
      acc[1][nf] = __builtin_amdgcn_mfma_f32_16x16x32_bf16(afr[1], bfr, acc[1][nf], 0, 0, 0); \
    }                                                                           \
  }

#define K1_ITER(T, WU, WL)                                                      \
  {                                                                             \
    VMCNT(9); SBAR();                                                           \
    K1_WLOAD(WL, (T) + 1);                                                      \
    if ((T) + 2 < 16) K1_STAGE((T) + 2, ((T) + 2) % 3);                         \
    K1_COMPUTE(T, WU);                                                          \
  }

__global__ __launch_bounds__(256, 3) void k1_logits(const float* __restrict__ feats,
                                                    const __bf16* __restrict__ Wfrag,
                                                    __bf16* __restrict__ E,
                                                    float* __restrict__ denom) {
  __shared__ float tile[3][32 * 128];  // 48 KB
  const int tid = threadIdx.x;
  const int lane = tid & 63, wave = tid >> 6;
  const int quad = lane >> 4, l16 = lane & 15;
  const int b = blockIdx.y;
  const int htile0 = blockIdx.x * 128;
  const float* fb = feats + (size_t)b * (C_ * HW_);
  const f32x4 zero = {0.f, 0.f, 0.f, 0.f};

  for (int rep = 0; rep < REPS; ++rep) {
    if (rep) { VMCNT(0); SBAR(); }  // reset pipeline state between reps

    f32x4 acc[2][5];
#pragma unroll
    for (int hf = 0; hf < 2; ++hf)
#pragma unroll
      for (int nf = 0; nf < 5; ++nf) acc[hf][nf] = zero;

    u16x8 wfA[5], wfB[5];
    K1_STAGE(0, 0);
    K1_WLOAD(wfA, 0);
    K1_STAGE(1, 1);

    for (int t = 0; t < 14; t += 2) {
      K1_ITER(t, wfA, wfB);
      K1_ITER(t + 1, wfB, wfA);
    }
    K1_ITER(14, wfA, wfB);
    VMCNT(5); SBAR();
    K1_COMPUTE(15, wfB);

#pragma unroll
    for (int nf = 0; nf < 5; ++nf) {
      const int n = nf * 16 + l16;
      float s = 0.f;
#pragma unroll
      for (int hf = 0; hf < 2; ++hf) {
        bf16x4 pk;
#pragma unroll
        for (int j = 0; j < 4; ++j) {
          const float e = __expf(acc[hf][nf][j]);
          s += e;
          pk[j] = (__bf16)e;
        }
        const int h = htile0 + wave * 32 + hf * 16 + quad * 4;
        *(bf16x4*)(E + (size_t)(b * N_ + n) * HW_ + h) = pk;
      }
      if (rep == REPS - 1) {
        s += __shfl_xor(s, 16);
        s += __shfl_xor(s, 32);
        if (lane < 16) atomicAdd(denom + b * N_ + nf * 16 + lane, s);
      }
    }
  }
}

// ---------------------------------------------------------------------------
// K3 (REPS-instrumented): out = (sum_h E * feats) / denom. Structure
// identical to R11. Grid 512 flat, 4 waves, 2 blocks/CU.
// ---------------------------------------------------------------------------
#define K3_STAGE(TK, SLOT)                                                      \
  {                                                                             \
    const int h0 = (TK)*64;                                                     \
    _Pragma("unroll") for (int j = 0; j < 2; ++j) {                             \
      const int d = j * 256 + tid;                                              \
      const int r = d >> 4, p = d & 15;                                         \
      gload_lds16(fb + (size_t)(c0 + r) * HW_ + h0 + ((p ^ (r & 15)) << 2),     \
                  (char*)fA + (SLOT)*8192 + (j * 256 + wave * 64) * 16);        \
    }                                                                           \
    _Pragma("unroll") for (int j = 0; j < 2; ++j) {                             \
      const int d = j * 256 + tid;                                              \
      const int r = d >> 3, p = d & 7;                                          \
      gload_lds16(eb + (size_t)r * HW_ + h0 + ((p ^ (r & 7)) << 3),             \
                  (char*)fB + (SLOT)*10240 + (j * 256 + wave * 64) * 16);       \
    }                                                                           \
    {                                                                           \
      const int d = 512 + (wave & 1) * 64 + lane;                               \
      const int r = d >> 3, p = d & 7;                                          \
      gload_lds16(eb + (size_t)r * HW_ + h0 + ((p ^ (r & 7)) << 3),             \
                  (char*)fB + (SLOT)*10240 + (512 + (wave & 1) * 64) * 16);     \
    }                                                                           \
  }

#define K3_COMPUTE(T)                                                           \
  {                                                                             \
    const float* A = (const float*)((char*)fA + ((T) % 4) * 8192);              \
    const __bf16* Bv = (const __bf16*)((char*)fB + ((T) % 4) * 10240);          \
    _Pragma("unroll") for (int ks = 0; ks < 2; ++ks) {                          \
      const int u0 = (ks * 8 + quad * 2) ^ l16;                                 \
      const int u1 = (ks * 8 + quad * 2 + 1) ^ l16;                             \
      const f32x4 va = *(const f32x4*)&A[rA * 64 + u0 * 4];                     \
      const f32x4 vb = *(const f32x4*)&A[rA * 64 + u1 * 4];                     \
      bf16x8 af;                                                                \
      af[0] = (__bf16)va[0]; af[1] = (__bf16)va[1];                             \
      af[2] = (__bf16)va[2]; af[3] = (__bf16)va[3];                             \
      af[4] = (__bf16)vb[0]; af[5] = (__bf16)vb[1];                             \
      af[6] = (__bf16)vb[2]; af[7] = (__bf16)vb[3];                             \
      _Pragma("unroll") for (int nfl = 0; nfl < 3; ++nfl) {                     \
        if (nfl >= nfcnt) break;                                                \
        const int n = (nfbase + nfl) * 16 + l16;                                \
        const int ub = (ks * 4 + quad) ^ (l16 & 7);                             \
        const u16x8 bv = *(const u16x8*)&Bv[n * 64 + ub * 8];                   \
        const bf16x8 bfr = __builtin_bit_cast(bf16x8, bv);                      \
        acc[nfl] = __builtin_amdgcn_mfma_f32_16x16x32_bf16(af, bfr, acc[nfl], 0, 0, 0); \
      }                                                                         \
    }                                                                           \
  }

__global__ __launch_bounds__(256, 2) void k3_pool(const float* __restrict__ feats,
                                                  const __bf16* __restrict__ E,
                                                  const float* __restrict__ denom,
                                                  float* __restrict__ out) {
  __shared__ float fA[4][32 * 64];    // 32 KB
  __shared__ __bf16 fB[4][80 * 64];   // 40 KB
  const int tid = threadIdx.x;
  const int lane = tid & 63, wave = tid >> 6;
  const int quad = lane >> 4, l16 = lane & 15;
  const int cf = wave & 1, ng = wave >> 1;
  const int nfbase = ng ? 3 : 0, nfcnt = ng ? 2 : 3;

  // XCD-chunked remap (bijective: 512 = 8 * 64)
  const int wg = blockIdx.x;
  const int nid = (wg & 7) * 64 + (wg >> 3);
  const int b = nid >> 4, cx = nid & 15;
  const int c0 = cx * 32;

  const float* fb = feats + (size_t)b * (C_ * HW_);
  const __bf16* eb = E + (size_t)b * N_ * HW_;
  const int rA = cf * 16 + l16;
  const f32x4 zero = {0.f, 0.f, 0.f, 0.f};

  for (int rep = 0; rep < REPS; ++rep) {
    if (rep) { VMCNT(0); SBAR(); }

    f32x4 acc[3];
#pragma unroll
    for (int i = 0; i < 3; ++i) acc[i] = zero;

    K3_STAGE(0, 0);
    K3_STAGE(1, 1);
    K3_STAGE(2, 2);

    for (int t = 0; t < 61; ++t) {
      VMCNT(10); SBAR();
      K3_STAGE(t + 3, (t + 3) & 3);
      K3_COMPUTE(t);
    }
    VMCNT(10); SBAR(); K3_COMPUTE(61);
    VMCNT(5);  SBAR(); K3_COMPUTE(62);
    VMCNT(0);  SBAR(); K3_COMPUTE(63);

#pragma unroll
    for (int nfl = 0; nfl < 3; ++nfl) {
      if (nfl >= nfcnt) break;
      const int n = (nfbase + nfl) * 16 + l16;
      const float r = 1.0f / denom[b * N_ + n];
      float4 v;
      v.x = acc[nfl][0] * r; v.y = acc[nfl][1] * r;
      v.z = acc[nfl][2] * r; v.w = acc[nfl][3] * r;
      *(float4*)(out + (size_t)(b * N_ + n) * C_ + c0 + cf * 16 + quad * 4) = v;
    }
  }
}

extern "C" void kernel_launch(void* const* d_in, const int* in_sizes, int n_in,
                              void* d_out, int out_size, void* d_ws, size_t ws_size,
                              hipStream_t stream) {
  (void)in_sizes; (void)n_in; (void)out_size; (void)ws_size;
  const float* feats = (const float*)d_in[0];
  const float* Wm = (const float*)d_in[1];
  float* out = (float*)d_out;

  __bf16* E = (__bf16*)d_ws;                    // 21 MB
  __bf16* Wfrag = E + (size_t)B_ * N_ * HW_;    // 80 KB
  float* denom = (float*)(Wfrag + 16 * 5 * 64 * 8);  // 10 KB

  hipLaunchKernelGGL(k0_wfrag, dim3(20), dim3(256), 0, stream, Wm, Wfrag, denom);
  hipLaunchKernelGGL(k1_logits, dim3(HW_ / 128, B_), dim3(256), 0, stream, feats, Wfrag, E, denom);
  hipLaunchKernelGGL(k3_pool, dim3(512), dim3(256), 0, stream, feats, E, denom, out);
}

// Round 15
// 154.225 us; speedup vs baseline: 2.7995x; 2.7995x over previous
//
#include <hip/hip_runtime.h>

#define B_ 32
#define C_ 512
#define HW_ 4096
#define N_ 80

typedef __bf16 bf16x8 __attribute__((ext_vector_type(8)));
typedef __bf16 bf16x4 __attribute__((ext_vector_type(4)));
typedef float f32x4 __attribute__((ext_vector_type(4)));
typedef unsigned short u16x8 __attribute__((ext_vector_type(8)));

__device__ __forceinline__ void gload_lds16(const void* g, void* l) {
  __builtin_amdgcn_global_load_lds((const __attribute__((address_space(1))) void*)g,
                                   (__attribute__((address_space(3))) void*)l, 16, 0, 0);
}

#define VMCNT(n) asm volatile("s_waitcnt vmcnt(" #n ")" ::: "memory")
#define SBAR() asm volatile("s_barrier" ::: "memory")

// ---------------------------------------------------------------------------
// K0: refragment W -> Wfrag bf16 (MFMA B-operand unit layout) AND zero denom.
// ---------------------------------------------------------------------------
__global__ __launch_bounds__(256) void k0_wfrag(const float* __restrict__ W,
                                                __bf16* __restrict__ Wfrag,
                                                float* __restrict__ denom) {
  const int t = blockIdx.x * 256 + threadIdx.x;
  if (t < B_ * N_) denom[t] = 0.f;
  if (t >= 16 * 5 * 64) return;
  const int cs = t / 320, rem = t % 320;
  const int nf = rem >> 6, lane = rem & 63;
  const int n = nf * 16 + (lane & 15);
  const int c = cs * 32 + (lane >> 4) * 8;
  const float* wp = W + (size_t)n * C_ + c;
  bf16x8 v;
#pragma unroll
  for (int i = 0; i < 8; ++i) v[i] = (__bf16)wp[i];
  *(bf16x8*)(Wfrag + (size_t)t * 8) = v;
}

// ---------------------------------------------------------------------------
// K1: E = exp(feats^T W^T); denom += row sums. UNCHANGED from R11 (measured
// at HBM roofline: 277 MB / 40 us = 6.4 TB/s). Grid (HW/128, B), 3 blocks/CU.
// ---------------------------------------------------------------------------
#define K1_STAGE(CS, SLOT)                                                      \
  {                                                                             \
    _Pragma("unroll") for (int j = 0; j < 4; ++j) {                             \
      const int d = j * 256 + tid;                                              \
      const int r = d >> 5, p = d & 31;                                         \
      gload_lds16(fb + (size_t)((CS)*32 + r) * HW_ + htile0 + p * 4,            \
                  (char*)tile + (SLOT)*16384 + (j * 256 + wave * 64) * 16);     \
    }                                                                           \
  }

#define K1_WLOAD(W, CS)                                                         \
  {                                                                             \
    _Pragma("unroll") for (int nf = 0; nf < 5; ++nf)                            \
        W[nf] = *(const u16x8*)(Wfrag + ((size_t)((CS)*5 + nf) * 64 + lane) * 8); \
  }

#define K1_COMPUTE(T, WU)                                                       \
  {                                                                             \
    const float* tb = (const float*)((char*)tile + ((T) % 3) * 16384);          \
    bf16x8 afr[2];                                                              \
    _Pragma("unroll") for (int hf = 0; hf < 2; ++hf) {                          \
      const int col = wave * 32 + hf * 16 + l16;                                \
      _Pragma("unroll") for (int i = 0; i < 8; ++i)                             \
          afr[hf][i] = (__bf16)tb[(quad * 8 + i) * 128 + col];                  \
    }                                                                           \
    _Pragma("unroll") for (int nf = 0; nf < 5; ++nf) {                          \
      const bf16x8 bfr = __builtin_bit_cast(bf16x8, WU[nf]);                    \
      acc[0][nf] = __builtin_amdgcn_mfma_f32_16x16x32_bf16(afr[0], bfr, acc[0][nf], 0, 0, 0); \
      acc[1][nf] = __builtin_amdgcn_mfma_f32_16x16x32_bf16(afr[1], bfr, acc[1][nf], 0, 0, 0); \
    }                                                                           \
  }

#define K1_ITER(T, WU, WL)                                                      \
  {                                                                             \
    VMCNT(9); SBAR();                                                           \
    K1_WLOAD(WL, (T) + 1);                                                      \
    if ((T) + 2 < 16) K1_STAGE((T) + 2, ((T) + 2) % 3);                         \
    K1_COMPUTE(T, WU);                                                          \
  }

__global__ __launch_bounds__(256, 3) void k1_logits(const float* __restrict__ feats,
                                                    const __bf16* __restrict__ Wfrag,
                                                    __bf16* __restrict__ E,
                                                    float* __restrict__ denom) {
  __shared__ float tile[3][32 * 128];  // 48 KB
  const int tid = threadIdx.x;
  const int lane = tid & 63, wave = tid >> 6;
  const int quad = lane >> 4, l16 = lane & 15;
  const int b = blockIdx.y;
  const int htile0 = blockIdx.x * 128;
  const float* fb = feats + (size_t)b * (C_ * HW_);

  const f32x4 zero = {0.f, 0.f, 0.f, 0.f};
  f32x4 acc[2][5];
#pragma unroll
  for (int hf = 0; hf < 2; ++hf)
#pragma unroll
    for (int nf = 0; nf < 5; ++nf) acc[hf][nf] = zero;

  u16x8 wfA[5], wfB[5];
  K1_STAGE(0, 0);
  K1_WLOAD(wfA, 0);
  K1_STAGE(1, 1);

  for (int t = 0; t < 14; t += 2) {
    K1_ITER(t, wfA, wfB);
    K1_ITER(t + 1, wfB, wfA);
  }
  K1_ITER(14, wfA, wfB);
  VMCNT(5); SBAR();
  K1_COMPUTE(15, wfB);

#pragma unroll
  for (int nf = 0; nf < 5; ++nf) {
    const int n = nf * 16 + l16;
    float s = 0.f;
#pragma unroll
    for (int hf = 0; hf < 2; ++hf) {
      bf16x4 pk;
#pragma unroll
      for (int j = 0; j < 4; ++j) {
        const float e = __expf(acc[hf][nf][j]);
        s += e;
        pk[j] = (__bf16)e;
      }
      const int h = htile0 + wave * 32 + hf * 16 + quad * 4;
      *(bf16x4*)(E + (size_t)(b * N_ + n) * HW_ + h) = pk;
    }
    s += __shfl_xor(s, 16);
    s += __shfl_xor(s, 32);
    if (lane < 16) atomicAdd(denom + b * N_ + nf * 16 + lane, s);
  }
}

// ---------------------------------------------------------------------------
// K3: out[b][n][c] = (sum_h E[b][n][h] * feats[b][c][h]) / denom[b][n]
// 16-waves/CU: 512 thr (8 waves), tile [32c][32h] f32 (4KB, 256 units) +
// [80n][32h] bf16 (5KB, 320 units), 4 slots = 36 KB LDS, 2 blocks/CU.
// Stage = 2 vm-events/wave: fA lanes<32 (8x32=256 units), fB lanes<40
// (8x40=320 units)  [R14 bug: was lanes<20 -> half of fB unstaged -> NaN].
// XOR source-swizzle: fA phys p holds logical p^(r&7); fB p^(r&3).
// Pipeline depth-3: [vmcnt(4); bar; stage(t+3); compute(t)]; tails 4/2/0.
// Waves: cf=w&1 (c half), ng=w>>1 -> nf groups {0,1},{2},{3},{4}.
// 128 iters. XCD-chunked remap (512 = 8*64). Grid 512 flat.
// ---------------------------------------------------------------------------
#define K3_STAGE(TK, SLOT)                                                      \
  {                                                                             \
    const int h0 = (TK)*32;                                                     \
    if (lane < 32) {                                                            \
      const int d = wave * 32 + lane;                                           \
      const int r = d >> 3, p = d & 7;                                          \
      gload_lds16(fb + (size_t)(c0 + r) * HW_ + h0 + ((p ^ (r & 7)) << 2),      \
                  (char*)fA + (SLOT)*4096 + wave * 512);                        \
    }                                                                           \
    if (lane < 40) {                                                            \
      const int d = wave * 40 + lane;                                           \
      const int r = d >> 2, p = d & 3;                                          \
      gload_lds16(eb + (size_t)r * HW_ + h0 + ((p ^ (r & 3)) << 3),             \
                  (char*)fB + (SLOT)*5120 + wave * 640);                        \
    }                                                                           \
  }

#define K3_COMPUTE(T)                                                           \
  {                                                                             \
    const float* A = (const float*)((char*)fA + ((T) & 3) * 4096);              \
    const __bf16* Bv = (const __bf16*)((char*)fB + ((T) & 3) * 5120);           \
    const int u0 = (quad * 2) ^ (l16 & 7);                                      \
    const int u1 = (quad * 2 + 1) ^ (l16 & 7);                                  \
    const f32x4 va = *(const f32x4*)&A[rA * 32 + u0 * 4];                       \
    const f32x4 vb = *(const f32x4*)&A[rA * 32 + u1 * 4];                       \
    bf16x8 af;                                                                  \
    af[0] = (__bf16)va[0]; af[1] = (__bf16)va[1];                               \
    af[2] = (__bf16)va[2]; af[3] = (__bf16)va[3];                               \
    af[4] = (__bf16)vb[0]; af[5] = (__bf16)vb[1];                               \
    af[6] = (__bf16)vb[2]; af[7] = (__bf16)vb[3];                               \
    _Pragma("unroll") for (int nfl = 0; nfl < 2; ++nfl) {                       \
      if (nfl >= nfcnt) break;                                                  \
      const int n = (nfbase + nfl) * 16 + l16;                                  \
      const int ub = quad ^ (l16 & 3);                                          \
      const u16x8 bv = *(const u16x8*)&Bv[n * 32 + ub * 8];                     \
      const bf16x8 bfr = __builtin_bit_cast(bf16x8, bv);                        \
      acc[nfl] = __builtin_amdgcn_mfma_f32_16x16x32_bf16(af, bfr, acc[nfl], 0, 0, 0); \
    }                                                                           \
  }

__global__ __launch_bounds__(512, 2) void k3_pool(const float* __restrict__ feats,
                                                  const __bf16* __restrict__ E,
                                                  const float* __restrict__ denom,
                                                  float* __restrict__ out) {
  __shared__ float fA[4 * 32 * 32];    // 16 KB (4 slots x 4 KB)
  __shared__ __bf16 fB[4 * 80 * 32];   // 20 KB (4 slots x 5 KB)
  const int tid = threadIdx.x;
  const int lane = tid & 63, wave = tid >> 6;
  const int quad = lane >> 4, l16 = lane & 15;
  const int cf = wave & 1, ng = wave >> 1;
  const int nfbase = (ng == 0) ? 0 : (ng + 1);
  const int nfcnt = (ng == 0) ? 2 : 1;

  // XCD-chunked remap (bijective: 512 = 8 * 64)
  const int wg = blockIdx.x;
  const int nid = (wg & 7) * 64 + (wg >> 3);
  const int b = nid >> 4, cx = nid & 15;
  const int c0 = cx * 32;

  const float* fb = feats + (size_t)b * (C_ * HW_);
  const __bf16* eb = E + (size_t)b * N_ * HW_;
  const int rA = cf * 16 + l16;
  const f32x4 zero = {0.f, 0.f, 0.f, 0.f};

  f32x4 acc[2];
  acc[0] = zero;
  acc[1] = zero;

  K3_STAGE(0, 0);
  K3_STAGE(1, 1);
  K3_STAGE(2, 2);

  for (int t = 0; t < 125; ++t) {
    VMCNT(4); SBAR();
    K3_STAGE(t + 3, (t + 3) & 3);
    K3_COMPUTE(t);
  }
  VMCNT(4); SBAR(); K3_COMPUTE(125);
  VMCNT(2); SBAR(); K3_COMPUTE(126);
  VMCNT(0); SBAR(); K3_COMPUTE(127);

  // Epilogue: divide by denom, write final out.
#pragma unroll
  for (int nfl = 0; nfl < 2; ++nfl) {
    if (nfl >= nfcnt) break;
    const int n = (nfbase + nfl) * 16 + l16;
    const float r = 1.0f / denom[b * N_ + n];
    float4 v;
    v.x = acc[nfl][0] * r; v.y = acc[nfl][1] * r;
    v.z = acc[nfl][2] * r; v.w = acc[nfl][3] * r;
    *(float4*)(out + (size_t)(b * N_ + n) * C_ + c0 + cf * 16 + quad * 4) = v;
  }
}

extern "C" void kernel_launch(void* const* d_in, const int* in_sizes, int n_in,
                              void* d_out, int out_size, void* d_ws, size_t ws_size,
                              hipStream_t stream) {
  (void)in_sizes; (void)n_in; (void)out_size; (void)ws_size;
  const float* feats = (const float*)d_in[0];
  const float* Wm = (const float*)d_in[1];
  float* out = (float*)d_out;

  __bf16* E = (__bf16*)d_ws;                    // 21 MB
  __bf16* Wfrag = E + (size_t)B_ * N_ * HW_;    // 80 KB
  float* denom = (float*)(Wfrag + 16 * 5 * 64 * 8);  // 10 KB

  hipLaunchKernelGGL(k0_wfrag, dim3(20), dim3(256), 0, stream, Wm, Wfrag, denom);
  hipLaunchKernelGGL(k1_logits, dim3(HW_ / 128, B_), dim3(256), 0, stream, feats, Wfrag, E, denom);
  hipLaunchKernelGGL(k3_pool, dim3(512), dim3(512), 0, stream, feats, E, denom, out);
}

// Round 16
// 151.390 us; speedup vs baseline: 2.8520x; 1.0187x over previous
//
#include <hip/hip_runtime.h>

#define B_ 32
#define C_ 512
#define HW_ 4096
#define N_ 80

typedef __bf16 bf16x8 __attribute__((ext_vector_type(8)));
typedef __bf16 bf16x4 __attribute__((ext_vector_type(4)));
typedef float f32x4 __attribute__((ext_vector_type(4)));
typedef unsigned short u16x8 __attribute__((ext_vector_type(8)));

__device__ __forceinline__ void gload_lds16(const void* g, void* l) {
  __builtin_amdgcn_global_load_lds((const __attribute__((address_space(1))) void*)g,
                                   (__attribute__((address_space(3))) void*)l, 16, 0, 0);
}

#define VMCNT(n) asm volatile("s_waitcnt vmcnt(" #n ")" ::: "memory")
#define SBAR() asm volatile("s_barrier" ::: "memory")

// ---------------------------------------------------------------------------
// K0: refragment W -> Wfrag bf16 (MFMA B-operand unit layout) AND zero denom.
// ---------------------------------------------------------------------------
__global__ __launch_bounds__(256) void k0_wfrag(const float* __restrict__ W,
                                                __bf16* __restrict__ Wfrag,
                                                float* __restrict__ denom) {
  const int t = blockIdx.x * 256 + threadIdx.x;
  if (t < B_ * N_) denom[t] = 0.f;
  if (t >= 16 * 5 * 64) return;
  const int cs = t / 320, rem = t % 320;
  const int nf = rem >> 6, lane = rem & 63;
  const int n = nf * 16 + (lane & 15);
  const int c = cs * 32 + (lane >> 4) * 8;
  const float* wp = W + (size_t)n * C_ + c;
  bf16x8 v;
#pragma unroll
  for (int i = 0; i < 8; ++i) v[i] = (__bf16)wp[i];
  *(bf16x8*)(Wfrag + (size_t)t * 8) = v;
}

// ---------------------------------------------------------------------------
// K1: E = exp(feats^T W^T); denom += row sums. FROZEN (measured at HBM
// roofline: 277 MB / 40 us = 6.4 TB/s). Grid (HW/128, B), 3 blocks/CU.
// ---------------------------------------------------------------------------
#define K1_STAGE(CS, SLOT)                                                      \
  {                                                                             \
    _Pragma("unroll") for (int j = 0; j < 4; ++j) {                             \
      const int d = j * 256 + tid;                                              \
      const int r = d >> 5, p = d & 31;                                         \
      gload_lds16(fb + (size_t)((CS)*32 + r) * HW_ + htile0 + p * 4,            \
                  (char*)tile + (SLOT)*16384 + (j * 256 + wave * 64) * 16);     \
    }                                                                           \
  }

#define K1_WLOAD(W, CS)                                                         \
  {                                                                             \
    _Pragma("unroll") for (int nf = 0; nf < 5; ++nf)                            \
        W[nf] = *(const u16x8*)(Wfrag + ((size_t)((CS)*5 + nf) * 64 + lane) * 8); \
  }

#define K1_COMPUTE(T, WU)                                                       \
  {                                                                             \
    const float* tb = (const float*)((char*)tile + ((T) % 3) * 16384);          \
    bf16x8 afr[2];                                                              \
    _Pragma("unroll") for (int hf = 0; hf < 2; ++hf) {                          \
      const int col = wave * 32 + hf * 16 + l16;                                \
      _Pragma("unroll") for (int i = 0; i < 8; ++i)                             \
          afr[hf][i] = (__bf16)tb[(quad * 8 + i) * 128 + col];                  \
    }                                                                           \
    _Pragma("unroll") for (int nf = 0; nf < 5; ++nf) {                          \
      const bf16x8 bfr = __builtin_bit_cast(bf16x8, WU[nf]);                    \
      acc[0][nf] = __builtin_amdgcn_mfma_f32_16x16x32_bf16(afr[0], bfr, acc[0][nf], 0, 0, 0); \
      acc[1][nf] = __builtin_amdgcn_mfma_f32_16x16x32_bf16(afr[1], bfr, acc[1][nf], 0, 0, 0); \
    }                                                                           \
  }

#define K1_ITER(T, WU, WL)                                                      \
  {                                                                             \
    VMCNT(9); SBAR();                                                           \
    K1_WLOAD(WL, (T) + 1);                                                      \
    if ((T) + 2 < 16) K1_STAGE((T) + 2, ((T) + 2) % 3);                         \
    K1_COMPUTE(T, WU);                                                          \
  }

__global__ __launch_bounds__(256, 3) void k1_logits(const float* __restrict__ feats,
                                                    const __bf16* __restrict__ Wfrag,
                                                    __bf16* __restrict__ E,
                                                    float* __restrict__ denom) {
  __shared__ float tile[3][32 * 128];  // 48 KB
  const int tid = threadIdx.x;
  const int lane = tid & 63, wave = tid >> 6;
  const int quad = lane >> 4, l16 = lane & 15;
  const int b = blockIdx.y;
  const int htile0 = blockIdx.x * 128;
  const float* fb = feats + (size_t)b * (C_ * HW_);

  const f32x4 zero = {0.f, 0.f, 0.f, 0.f};
  f32x4 acc[2][5];
#pragma unroll
  for (int hf = 0; hf < 2; ++hf)
#pragma unroll
    for (int nf = 0; nf < 5; ++nf) acc[hf][nf] = zero;

  u16x8 wfA[5], wfB[5];
  K1_STAGE(0, 0);
  K1_WLOAD(wfA, 0);
  K1_STAGE(1, 1);

  for (int t = 0; t < 14; t += 2) {
    K1_ITER(t, wfA, wfB);
    K1_ITER(t + 1, wfB, wfA);
  }
  K1_ITER(14, wfA, wfB);
  VMCNT(5); SBAR();
  K1_COMPUTE(15, wfB);

#pragma unroll
  for (int nf = 0; nf < 5; ++nf) {
    const int n = nf * 16 + l16;
    float s = 0.f;
#pragma unroll
    for (int hf = 0; hf < 2; ++hf) {
      bf16x4 pk;
#pragma unroll
      for (int j = 0; j < 4; ++j) {
        const float e = __expf(acc[hf][nf][j]);
        s += e;
        pk[j] = (__bf16)e;
      }
      const int h = htile0 + wave * 32 + hf * 16 + quad * 4;
      *(bf16x4*)(E + (size_t)(b * N_ + n) * HW_ + h) = pk;
    }
    s += __shfl_xor(s, 16);
    s += __shfl_xor(s, 32);
    if (lane < 16) atomicAdd(denom + b * N_ + nf * 16 + lane, s);
  }
}

// ---------------------------------------------------------------------------
// K3-C: out[b][n][c] = (sum_h E[b][n][h] * feats[b][c][h]) / denom[b][n]
// feats-only LDS: fA [32c][128h] f32 (16 KB, 512B/row chunks = K1's proven
// width), 4 slots = 64 KB, 2 blocks/CU (8 waves/CU; VGPR free to 256).
// E (L2/L3-resident: 2.6 MB/XCD with remap) prefetched DIRECTLY to registers
// one iter ahead (named sets bfA/bfB). XOR source-swizzle fA: phys p holds
// logical p^(r&15) -> b128 reads conflict-free.
// FIFO (per wave): B(t)[<=12ev], S(t+2)[4ev] | at iter t: vmcnt(4) ->
// B(t), S(t) complete. Iter = [vmcnt; bar; BFRAG(t+1); STAGE(t+3); compute].
// 32 iters of 128h. Waves: cf=w&1 (c-half), ng=w>>1 (nf {0,1,2}|{3,4}).
// Grid 512 flat, XCD-chunked remap (512 = 8*64).
// ---------------------------------------------------------------------------
#define K3_STAGE(T, SLOT)                                                       \
  {                                                                             \
    _Pragma("unroll") for (int j = 0; j < 4; ++j) {                             \
      const int d = j * 256 + tid;                                              \
      const int r = d >> 5, p = d & 31;                                         \
      gload_lds16(fb + (size_t)(c0 + r) * HW_ + (T)*128 + ((p ^ (r & 15)) << 2), \
                  (char*)fA + (SLOT)*16384 + (j * 256 + wave * 64) * 16);       \
    }                                                                           \
  }

#define K3_BFRAG(DST, T)                                                        \
  {                                                                             \
    _Pragma("unroll") for (int ks_ = 0; ks_ < 4; ++ks_)                         \
    _Pragma("unroll") for (int nf_ = 0; nf_ < 3; ++nf_)                         \
      if (nf_ < nfcnt) {                                                        \
        const int n_ = (nfbase + nf_) * 16 + l16;                               \
        DST[ks_][nf_] =                                                         \
            *(const u16x8*)(eb + (size_t)n_ * HW_ + (T)*128 + ks_ * 32 + quad * 8); \
      }                                                                         \
  }

#define K3_COMPUTE(T, BFS)                                                      \
  {                                                                             \
    const float* A = (const float*)((char*)fA + ((T)&3) * 16384);               \
    _Pragma("unroll") for (int ks_ = 0; ks_ < 4; ++ks_) {                       \
      const int u0 = (ks_ * 8 + quad * 2) ^ (rA & 15);                          \
      const int u1 = (ks_ * 8 + quad * 2 + 1) ^ (rA & 15);                      \
      const f32x4 va = *(const f32x4*)&A[rA * 128 + u0 * 4];                    \
      const f32x4 vb = *(const f32x4*)&A[rA * 128 + u1 * 4];                    \
      bf16x8 af;                                                                \
      af[0] = (__bf16)va[0]; af[1] = (__bf16)va[1];                             \
      af[2] = (__bf16)va[2]; af[3] = (__bf16)va[3];                             \
      af[4] = (__bf16)vb[0]; af[5] = (__bf16)vb[1];                             \
      af[6] = (__bf16)vb[2]; af[7] = (__bf16)vb[3];                             \
      _Pragma("unroll") for (int nf_ = 0; nf_ < 3; ++nf_)                       \
        if (nf_ < nfcnt) {                                                      \
          const bf16x8 bfr = __builtin_bit_cast(bf16x8, BFS[ks_][nf_]);         \
          acc[nf_] = __builtin_amdgcn_mfma_f32_16x16x32_bf16(af, bfr, acc[nf_], 0, 0, 0); \
        }                                                                       \
    }                                                                           \
  }

#define K3_ITER(T, USE, LOADDST)                                                \
  {                                                                             \
    VMCNT(4); SBAR();                                                           \
    K3_BFRAG(LOADDST, (T) + 1);                                                 \
    K3_STAGE((T) + 3, ((T) + 3) & 3);                                           \
    K3_COMPUTE(T, USE);                                                         \
  }

__global__ __launch_bounds__(256) void k3_pool(const float* __restrict__ feats,
                                               const __bf16* __restrict__ E,
                                               const float* __restrict__ denom,
                                               float* __restrict__ out) {
  __shared__ float fA[4 * 32 * 128];  // 64 KB (4 slots x 16 KB)
  const int tid = threadIdx.x;
  const int lane = tid & 63, wave = tid >> 6;
  const int quad = lane >> 4, l16 = lane & 15;
  const int cf = wave & 1, ng = wave >> 1;
  const int nfbase = ng ? 3 : 0, nfcnt = ng ? 2 : 3;

  // XCD-chunked remap (bijective: 512 = 8 * 64): 4 b's per XCD -> E L2-hot.
  const int wg = blockIdx.x;
  const int nid = (wg & 7) * 64 + (wg >> 3);
  const int b = nid >> 4, cx = nid & 15;
  const int c0 = cx * 32;

  const float* fb = feats + (size_t)b * (C_ * HW_);
  const __bf16* eb = E + (size_t)b * N_ * HW_;
  const int rA = cf * 16 + l16;
  const f32x4 zero = {0.f, 0.f, 0.f, 0.f};

  f32x4 acc[3];
#pragma unroll
  for (int i = 0; i < 3; ++i) acc[i] = zero;

  u16x8 bfA[4][3], bfB[4][3];
  // Prologue FIFO: B0 FIRST so iter-0's vmcnt(8) (= S1+S2 newer) covers it.
  K3_BFRAG(bfA, 0);
  K3_STAGE(0, 0);
  K3_STAGE(1, 1);
  K3_STAGE(2, 2);

  // iter 0: newer-than-S0 = S1,S2 = 8 events
  VMCNT(8); SBAR();
  K3_BFRAG(bfB, 1);
  K3_STAGE(3, 3);
  K3_COMPUTE(0, bfA);

  for (int t = 1; t < 28; t += 2) {
    K3_ITER(t, bfB, bfA);
    K3_ITER(t + 1, bfA, bfB);
  }
  // t=29 (odd -> bfB): stages done (S31 issued at t=28)
  VMCNT(4); SBAR();
  K3_BFRAG(bfA, 30);
  K3_COMPUTE(29, bfB);
  // t=30: newest outstanding = B30 -> drain
  VMCNT(0); SBAR();
  K3_BFRAG(bfB, 31);
  K3_COMPUTE(30, bfA);
  // t=31
  VMCNT(0); SBAR();
  K3_COMPUTE(31, bfB);

  // Epilogue: divide by denom, write final out.
#pragma unroll
  for (int nfl = 0; nfl < 3; ++nfl) {
    if (nfl >= nfcnt) break;
    const int n = (nfbase + nfl) * 16 + l16;
    const float r = 1.0f / denom[b * N_ + n];
    float4 v;
    v.x = acc[nfl][0] * r; v.y = acc[nfl][1] * r;
    v.z = acc[nfl][2] * r; v.w = acc[nfl][3] * r;
    *(float4*)(out + (size_t)(b * N_ + n) * C_ + c0 + cf * 16 + quad * 4) = v;
  }
}

extern "C" void kernel_launch(void* const* d_in, const int* in_sizes, int n_in,
                              void* d_out, int out_size, void* d_ws, size_t ws_size,
                              hipStream_t stream) {
  (void)in_sizes; (void)n_in; (void)out_size; (void)ws_size;
  const float* feats = (const float*)d_in[0];
  const float* Wm = (const float*)d_in[1];
  float* out = (float*)d_out;

  __bf16* E = (__bf16*)d_ws;                    // 21 MB
  __bf16* Wfrag = E + (size_t)B_ * N_ * HW_;    // 80 KB
  float* denom = (float*)(Wfrag + 16 * 5 * 64 * 8);  // 10 KB

  hipLaunchKernelGGL(k0_wfrag, dim3(20), dim3(256), 0, stream, Wm, Wfrag, denom);
  hipLaunchKernelGGL(k1_logits, dim3(HW_ / 128, B_), dim3(256), 0, stream, feats, Wfrag, E, denom);
  hipLaunchKernelGGL(k3_pool, dim3(512), dim3(256), 0, stream, feats, E, denom, out);
}

// Round 17
// 112.941 us; speedup vs baseline: 3.8229x; 1.3404x over previous
//
#include <hip/hip_runtime.h>

#define B_ 32
#define C_ 512
#define HW_ 4096
#define N_ 80

typedef __bf16 bf16x8 __attribute__((ext_vector_type(8)));
typedef __bf16 bf16x4 __attribute__((ext_vector_type(4)));
typedef float f32x4 __attribute__((ext_vector_type(4)));
typedef unsigned short u16x8 __attribute__((ext_vector_type(8)));

__device__ __forceinline__ void gload_lds16(const void* g, void* l) {
  __builtin_amdgcn_global_load_lds((const __attribute__((address_space(1))) void*)g,
                                   (__attribute__((address_space(3))) void*)l, 16, 0, 0);
}

#define VMCNT(n) asm volatile("s_waitcnt vmcnt(" #n ")" ::: "memory")
#define SBAR() asm volatile("s_barrier" ::: "memory")

// ---------------------------------------------------------------------------
// K0: refragment W -> Wfrag bf16 (MFMA B-operand unit layout) AND zero denom.
// ---------------------------------------------------------------------------
__global__ __launch_bounds__(256) void k0_wfrag(const float* __restrict__ W,
                                                __bf16* __restrict__ Wfrag,
                                                float* __restrict__ denom) {
  const int t = blockIdx.x * 256 + threadIdx.x;
  if (t < B_ * N_) denom[t] = 0.f;
  if (t >= 16 * 5 * 64) return;
  const int cs = t / 320, rem = t % 320;
  const int nf = rem >> 6, lane = rem & 63;
  const int n = nf * 16 + (lane & 15);
  const int c = cs * 32 + (lane >> 4) * 8;
  const float* wp = W + (size_t)n * C_ + c;
  bf16x8 v;
#pragma unroll
  for (int i = 0; i < 8; ++i) v[i] = (__bf16)wp[i];
  *(bf16x8*)(Wfrag + (size_t)t * 8) = v;
}

// ---------------------------------------------------------------------------
// K1: Efrag[(b*128+hc)*5+nf][lane] = exp-fragments; denom += row sums.
// Core loop FROZEN (R11, measured 6.4 TB/s). Epilogue now writes E in K3's
// MFMA B-operand unit order (Wfrag pattern): lane (quad,l16) of unit
// (b,hc,nf) holds E[nf*16+l16][hc*32+quad*8 ..+8]. K1's D-frag gives each
// lane only 4 h -> per-wave LDS bounce via [16n][72h] padded scratch in the
// dead tile slot 1 (2-way banks on write; epilogue-once 8-way on read: ok).
// Grid (HW/128, B), 4 waves, 3 blocks/CU (48 KB LDS).
// ---------------------------------------------------------------------------
#define K1_STAGE(CS, SLOT)                                                      \
  {                                                                             \
    _Pragma("unroll") for (int j = 0; j < 4; ++j) {                             \
      const int d = j * 256 + tid;                                              \
      const int r = d >> 5, p = d & 31;                                         \
      gload_lds16(fb + (size_t)((CS)*32 + r) * HW_ + htile0 + p * 4,            \
                  (char*)tile + (SLOT)*16384 + (j * 256 + wave * 64) * 16);     \
    }                                                                           \
  }

#define K1_WLOAD(W, CS)                                                         \
  {                                                                             \
    _Pragma("unroll") for (int nf = 0; nf < 5; ++nf)                            \
        W[nf] = *(const u16x8*)(Wfrag + ((size_t)((CS)*5 + nf) * 64 + lane) * 8); \
  }

#define K1_COMPUTE(T, WU)                                                       \
  {                                                                             \
    const float* tb = (const float*)((char*)tile + ((T) % 3) * 16384);          \
    bf16x8 afr[2];                                                              \
    _Pragma("unroll") for (int hf = 0; hf < 2; ++hf) {                          \
      const int col = wave * 32 + hf * 16 + l16;                                \
      _Pragma("unroll") for (int i = 0; i < 8; ++i)                             \
          afr[hf][i] = (__bf16)tb[(quad * 8 + i) * 128 + col];                  \
    }                                                                           \
    _Pragma("unroll") for (int nf = 0; nf < 5; ++nf) {                          \
      const bf16x8 bfr = __builtin_bit_cast(bf16x8, WU[nf]);                    \
      acc[0][nf] = __builtin_amdgcn_mfma_f32_16x16x32_bf16(afr[0], bfr, acc[0][nf], 0, 0, 0); \
      acc[1][nf] = __builtin_amdgcn_mfma_f32_16x16x32_bf16(afr[1], bfr, acc[1][nf], 0, 0, 0); \
    }                                                                           \
  }

#define K1_ITER(T, WU, WL)                                                      \
  {                                                                             \
    VMCNT(9); SBAR();                                                           \
    K1_WLOAD(WL, (T) + 1);                                                      \
    if ((T) + 2 < 16) K1_STAGE((T) + 2, ((T) + 2) % 3);                         \
    K1_COMPUTE(T, WU);                                                          \
  }

__global__ __launch_bounds__(256, 3) void k1_logits(const float* __restrict__ feats,
                                                    const __bf16* __restrict__ Wfrag,
                                                    __bf16* __restrict__ Efrag,
                                                    float* __restrict__ denom) {
  __shared__ float tile[3][32 * 128];  // 48 KB
  const int tid = threadIdx.x;
  const int lane = tid & 63, wave = tid >> 6;
  const int quad = lane >> 4, l16 = lane & 15;
  const int b = blockIdx.y;
  const int htile0 = blockIdx.x * 128;
  const float* fb = feats + (size_t)b * (C_ * HW_);

  const f32x4 zero = {0.f, 0.f, 0.f, 0.f};
  f32x4 acc[2][5];
#pragma unroll
  for (int hf = 0; hf < 2; ++hf)
#pragma unroll
    for (int nf = 0; nf < 5; ++nf) acc[hf][nf] = zero;

  u16x8 wfA[5], wfB[5];
  K1_STAGE(0, 0);
  K1_WLOAD(wfA, 0);
  K1_STAGE(1, 1);

  for (int t = 0; t < 14; t += 2) {
    K1_ITER(t, wfA, wfB);
    K1_ITER(t + 1, wfB, wfA);
  }
  K1_ITER(14, wfA, wfB);
  VMCNT(5); SBAR();
  K1_COMPUTE(15, wfB);

  // Epilogue: exp -> per-wave scratch bounce -> Efrag units + denom atomics.
  // Scratch: [16n][72h] bf16 per wave in dead tile slot 1 (no cross-wave use).
  __bf16* sw = (__bf16*)((char*)tile + 16384 + wave * 2304);
  const int hc = (htile0 >> 5) + wave;  // this wave's global 32-h chunk
#pragma unroll
  for (int nf = 0; nf < 5; ++nf) {
    const int n = nf * 16 + l16;
    float s = 0.f;
#pragma unroll
    for (int hf = 0; hf < 2; ++hf) {
      bf16x4 pk;
#pragma unroll
      for (int j = 0; j < 4; ++j) {
        const float e = __expf(acc[hf][nf][j]);
        s += e;
        pk[j] = (__bf16)e;
      }
      // D-frag: lane holds E[n=l16-row][h_local = hf*16+quad*4 ..+4]
      *(bf16x4*)&sw[l16 * 72 + hf * 16 + quad * 4] = pk;
    }
    s += __shfl_xor(s, 16);
    s += __shfl_xor(s, 32);
    if (lane < 16) atomicAdd(denom + b * N_ + nf * 16 + lane, s);
    // B-frag unit: lane (quad,l16) takes E[n=l16][quad*8 ..+8]
    const bf16x8 u = *(const bf16x8*)&sw[l16 * 72 + quad * 8];
    *(bf16x8*)(Efrag + (((size_t)(b * 128 + hc) * 5 + nf) * 64 + lane) * 8) = u;
  }
}

// ---------------------------------------------------------------------------
// K3-D: out[b][n][c] = (sum_h E * feats) / denom.
// A: feats f32 LDS [16c][128h]/slot (8 KB), XOR src-swizzle p^=r (refcheck'd
// R16), 4 slots = 32 KB -> 4 blocks/CU = 16 waves/CU. 32 iters of 128 h.
// B: COALESCED register prefetch from Efrag (named sets bfA/bfB), 1 ahead.
// Waves: nf groups {0,1},{2},{3},{4} (nfbase/nfcnt); all share c-tile 16.
// FIFO/wave: iter t = [vmcnt(2); bar; BFRAG(t+1); STAGE(t+3); compute(t)]
//   outstanding at wait: S(t+1)[2], B(t)[<=8], S(t+2)[2] -> vmcnt(2) leaves
//   S(t+2): B(t)+S(t) complete; stage budget 3 iters. Tails 2/0/0.
// Grid 1024 flat, bijective XCD remap (1024 = 8*128 -> 4 b's per XCD, Efrag
// slice 2.6 MB L2-resident).
// ---------------------------------------------------------------------------
#define K3_STAGE(T, SLOT)                                                       \
  {                                                                             \
    _Pragma("unroll") for (int j = 0; j < 2; ++j) {                             \
      const int d = j * 256 + tid;                                              \
      const int r = d >> 5, p = d & 31;                                         \
      gload_lds16(fb + (size_t)(c0 + r) * HW_ + (T)*128 + ((p ^ r) << 2),       \
                  (char*)fA + (SLOT)*8192 + (j * 256 + wave * 64) * 16);        \
    }                                                                           \
  }

#define K3_BFRAG(DST, T)                                                        \
  {                                                                             \
    _Pragma("unroll") for (int ks_ = 0; ks_ < 4; ++ks_)                         \
    _Pragma("unroll") for (int f_ = 0; f_ < 2; ++f_)                            \
      if (f_ < nfcnt)                                                           \
        DST[ks_][f_] = *(const u16x8*)(Efrag +                                  \
            (((size_t)(b * 128 + (T)*4 + ks_) * 5 + nfbase + f_) * 64 + lane) * 8); \
  }

#define K3_COMPUTE(T, BFS)                                                      \
  {                                                                             \
    const float* A = (const float*)((char*)fA + ((T)&3) * 8192);                \
    _Pragma("unroll") for (int ks_ = 0; ks_ < 4; ++ks_) {                       \
      const int u0 = (ks_ * 8 + quad * 2) ^ l16;                                \
      const int u1 = (ks_ * 8 + quad * 2 + 1) ^ l16;                            \
      const f32x4 va = *(const f32x4*)&A[l16 * 128 + u0 * 4];                   \
      const f32x4 vb = *(const f32x4*)&A[l16 * 128 + u1 * 4];                   \
      bf16x8 af;                                                                \
      af[0] = (__bf16)va[0]; af[1] = (__bf16)va[1];                             \
      af[2] = (__bf16)va[2]; af[3] = (__bf16)va[3];                             \
      af[4] = (__bf16)vb[0]; af[5] = (__bf16)vb[1];                             \
      af[6] = (__bf16)vb[2]; af[7] = (__bf16)vb[3];                             \
      _Pragma("unroll") for (int f_ = 0; f_ < 2; ++f_)                          \
        if (f_ < nfcnt) {                                                       \
          const bf16x8 bfr = __builtin_bit_cast(bf16x8, BFS[ks_][f_]);          \
          acc[f_] = __builtin_amdgcn_mfma_f32_16x16x32_bf16(af, bfr, acc[f_], 0, 0, 0); \
        }                                                                       \
    }                                                                           \
  }

#define K3_ITER(T, USE, LOADDST)                                                \
  {                                                                             \
    VMCNT(2); SBAR();                                                           \
    K3_BFRAG(LOADDST, (T) + 1);                                                 \
    if ((T) + 3 < 32) K3_STAGE((T) + 3, ((T) + 3) & 3);                         \
    K3_COMPUTE(T, USE);                                                         \
  }

__global__ __launch_bounds__(256, 4) void k3_pool(const float* __restrict__ feats,
                                                  const __bf16* __restrict__ Efrag,
                                                  const float* __restrict__ denom,
                                                  float* __restrict__ out) {
  __shared__ float fA[4 * 16 * 128];  // 32 KB (4 slots x 8 KB)
  const int tid = threadIdx.x;
  const int lane = tid & 63, wave = tid >> 6;
  const int quad = lane >> 4, l16 = lane & 15;
  const int nfbase = (wave == 0) ? 0 : (wave + 1);
  const int nfcnt = (wave == 0) ? 2 : 1;

  // XCD-chunked remap (bijective: 1024 = 8 * 128): 4 b's per XCD.
  const int wg = blockIdx.x;
  const int nid = (wg & 7) * 128 + (wg >> 3);
  const int b = nid >> 5, cx = nid & 31;
  const int c0 = cx * 16;

  const float* fb = feats + (size_t)b * (C_ * HW_);
  const f32x4 zero = {0.f, 0.f, 0.f, 0.f};

  f32x4 acc[2];
  acc[0] = zero;
  acc[1] = zero;

  u16x8 bfA[4][2], bfB[4][2];
  // Prologue FIFO: B0 oldest, then S0,S1,S2.
  K3_BFRAG(bfA, 0);
  K3_STAGE(0, 0);
  K3_STAGE(1, 1);
  K3_STAGE(2, 2);

  for (int t = 0; t < 28; t += 2) {
    K3_ITER(t, bfA, bfB);
    K3_ITER(t + 1, bfB, bfA);
  }
  K3_ITER(28, bfA, bfB);  // loads B29, stages S31
  // t=29 (uses bfB, loads bfA=B30)
  VMCNT(2); SBAR();
  K3_BFRAG(bfA, 30);
  K3_COMPUTE(29, bfB);
  // t=30 (uses bfA, loads bfB=B31): B30 is newest -> drain
  VMCNT(0); SBAR();
  K3_BFRAG(bfB, 31);
  K3_COMPUTE(30, bfA);
  // t=31
  VMCNT(0); SBAR();
  K3_COMPUTE(31, bfB);

  // Epilogue: divide by denom, write final out.
#pragma unroll
  for (int f = 0; f < 2; ++f) {
    if (f >= nfcnt) break;
    const int n = (nfbase + f) * 16 + l16;
    const float r = 1.0f / denom[b * N_ + n];
    float4 v;
    v.x = acc[f][0] * r; v.y = acc[f][1] * r;
    v.z = acc[f][2] * r; v.w = acc[f][3] * r;
    *(float4*)(out + (size_t)(b * N_ + n) * C_ + c0 + quad * 4) = v;
  }
}

extern "C" void kernel_launch(void* const* d_in, const int* in_sizes, int n_in,
                              void* d_out, int out_size, void* d_ws, size_t ws_size,
                              hipStream_t stream) {
  (void)in_sizes; (void)n_in; (void)out_size; (void)ws_size;
  const float* feats = (const float*)d_in[0];
  const float* Wm = (const float*)d_in[1];
  float* out = (float*)d_out;

  __bf16* Efrag = (__bf16*)d_ws;                   // 21 MB
  __bf16* Wfrag = Efrag + (size_t)B_ * N_ * HW_;   // 80 KB
  float* denom = (float*)(Wfrag + 16 * 5 * 64 * 8);  // 10 KB

  hipLaunchKernelGGL(k0_wfrag, dim3(20), dim3(256), 0, stream, Wm, Wfrag, denom);
  hipLaunchKernelGGL(k1_logits, dim3(HW_ / 128, B_), dim3(256), 0, stream, feats, Wfrag, Efrag, denom);
  hipLaunchKernelGGL(k3_pool, dim3(1024), dim3(256), 0, stream, feats, Efrag, denom, out);
}